// Round 6
// baseline (1535.659 us; speedup 1.0000x reference)
//
#include <hip/hip_runtime.h>

#define T_LEN 2048
#define HID 64
#define NG 256     // 4*HID gate rows per layer
#define EMB 128
#define NITER (T_LEN + 4)   // even — 2x unroll needs this

typedef _Float16 half2_t __attribute__((ext_vector_type(2)));

#if __has_builtin(__builtin_amdgcn_exp2f)
#define EXP2F(x) __builtin_amdgcn_exp2f(x)
#else
#define EXP2F(x) exp2f(x)
#endif
#if __has_builtin(__builtin_amdgcn_rcpf)
#define RCPF(x) __builtin_amdgcn_rcpf(x)
#else
#define RCPF(x) (1.0f / (x))
#endif

#define LOG2E 1.4426950408889634f

// v_dot2_f32_f16: 2-way f16 dot, f32 accumulate.
__device__ __forceinline__ float fdot2(uint32_t a, uint32_t b, float c) {
    return __builtin_amdgcn_fdot2(__builtin_bit_cast(half2_t, a),
                                  __builtin_bit_cast(half2_t, b), c, false);
}

// Quad broadcast via DPP quad_perm (VALU pipe; R4 showed __shfl = LDS pipe = slow).
template <int CTRL>
__device__ __forceinline__ float qbcast(float v) {
    int r = __builtin_amdgcn_update_dpp(0, __builtin_bit_cast(int, v),
                                        CTRL, 0xF, 0xF, true);
    return __builtin_bit_cast(float, r);
}

// 64 f16 of h held in 8 named uint4 registers (from 8x ds_read_b128 broadcast).
struct HV { uint4 h0, h1, h2, h3, h4, h5, h6, h7; };

__device__ __forceinline__ HV load_h8(const uint4* p) {
    HV v;
    v.h0 = p[0]; v.h1 = p[1]; v.h2 = p[2]; v.h3 = p[3];
    v.h4 = p[4]; v.h5 = p[5]; v.h6 = p[6]; v.h7 = p[7];
    return v;
}

// 64-MAC dot, 4 partial accumulators, fed directly from the HV registers.
__device__ __forceinline__ float dot64v(const uint32_t* w, const HV& v, float a0) {
    float a1 = 0.f, a2 = 0.f, a3 = 0.f;
    a0 = fdot2(w[ 0], v.h0.x, a0); a1 = fdot2(w[ 1], v.h0.y, a1);
    a2 = fdot2(w[ 2], v.h0.z, a2); a3 = fdot2(w[ 3], v.h0.w, a3);
    a0 = fdot2(w[ 4], v.h1.x, a0); a1 = fdot2(w[ 5], v.h1.y, a1);
    a2 = fdot2(w[ 6], v.h1.z, a2); a3 = fdot2(w[ 7], v.h1.w, a3);
    a0 = fdot2(w[ 8], v.h2.x, a0); a1 = fdot2(w[ 9], v.h2.y, a1);
    a2 = fdot2(w[10], v.h2.z, a2); a3 = fdot2(w[11], v.h2.w, a3);
    a0 = fdot2(w[12], v.h3.x, a0); a1 = fdot2(w[13], v.h3.y, a1);
    a2 = fdot2(w[14], v.h3.z, a2); a3 = fdot2(w[15], v.h3.w, a3);
    a0 = fdot2(w[16], v.h4.x, a0); a1 = fdot2(w[17], v.h4.y, a1);
    a2 = fdot2(w[18], v.h4.z, a2); a3 = fdot2(w[19], v.h4.w, a3);
    a0 = fdot2(w[20], v.h5.x, a0); a1 = fdot2(w[21], v.h5.y, a1);
    a2 = fdot2(w[22], v.h5.z, a2); a3 = fdot2(w[23], v.h5.w, a3);
    a0 = fdot2(w[24], v.h6.x, a0); a1 = fdot2(w[25], v.h6.y, a1);
    a2 = fdot2(w[26], v.h6.z, a2); a3 = fdot2(w[27], v.h6.w, a3);
    a0 = fdot2(w[28], v.h7.x, a0); a1 = fdot2(w[29], v.h7.y, a1);
    a2 = fdot2(w[30], v.h7.z, a2); a3 = fdot2(w[31], v.h7.w, a3);
    return (a0 + a1) + (a2 + a3);
}

// One 64-float weight row -> 32 packed f16 pairs, pre-scaled by `scale`
// (the exp2-space fold: sigmoid rows x -log2e, tanh rows x -2log2e).
__device__ __forceinline__ void cvt_row(const float* __restrict__ W, int row,
                                        float scale, uint32_t* dst) {
    const float4* W4 = reinterpret_cast<const float4*>(W + row * HID);
    #pragma unroll
    for (int k = 0; k < 16; ++k) {
        float4 v = W4[k];
        half2_t a{(_Float16)(v.x * scale), (_Float16)(v.y * scale)};
        half2_t b{(_Float16)(v.z * scale), (_Float16)(v.w * scale)};
        dst[2 * k]     = __builtin_bit_cast(uint32_t, a);
        dst[2 * k + 1] = __builtin_bit_cast(uint32_t, b);
    }
}

// One block per batch; 768 threads = 3 stages x 4 waves. Lane map (R5):
// lane = hloc*4 + cls; quad holds the 4 gate classes of one h-index -> DPP
// exchange; ONE barrier/iter. 5-task pipeline (R3 schedule). This round:
// 2x unroll (compile-time ring slots, all LDS addrs hoisted to pre-offset
// pointers), exp2-space weight prescale (no sE mul), unconditional p-writes
// (boundary garbage dies in act=false lanes), xs zero-padded (no clamp).
__global__ __launch_bounds__(768, 3) void lstm3_fused(
    const float* __restrict__ x,
    const float* __restrict__ Wih0, const float* __restrict__ Whh0,
    const float* __restrict__ bih0, const float* __restrict__ bhh0,
    const float* __restrict__ Wih1, const float* __restrict__ Whh1,
    const float* __restrict__ bih1, const float* __restrict__ bhh1,
    const float* __restrict__ Wih2, const float* __restrict__ Whh2,
    const float* __restrict__ bih2, const float* __restrict__ bhh2,
    const float* __restrict__ fcW,  const float* __restrict__ fcb,
    float* __restrict__ out)
{
    const int b     = blockIdx.x;
    const int tid   = threadIdx.x;
    const int stage = tid >> 8;        // 0,1,2 (wave-uniform)
    const int lane  = tid & 63;
    const int wv    = (tid >> 6) & 3;  // wave within stage
    const int hloc  = lane >> 2;       // 0..15
    const int cls   = lane & 3;        // 0=i,1=f,2=g,3=o
    const int hidx  = wv * 16 + hloc;  // h index [0,64)
    const int row   = cls * HID + hidx;// gate row [0,256)
    const int pidx  = hidx * 4 + cls;  // p-buffer slot ([2][NG]: 2-way, free)
    const bool cls0 = (cls == 0);

    __shared__ __align__(16) _Float16 h0f[2][HID];
    __shared__ __align__(16) _Float16 h1f[2][HID];
    __shared__ __align__(16) _Float16 h2f[2][HID];
    __shared__ float p1buf[2][NG], p2buf[2][NG];
    __shared__ __align__(16) float xs[NITER];     // padded to NITER (zeros)

    // Stage x[b,0,:] into LDS; zero the 4-float pad.
    {
        const float4* xg4 = reinterpret_cast<const float4*>(x + b * T_LEN);
        float4* xs4 = reinterpret_cast<float4*>(xs);
        if (tid < T_LEN / 4) xs4[tid] = xg4[tid];
        if (tid == 768 - 1) xs4[T_LEN / 4] = make_float4(0.f, 0.f, 0.f, 0.f);
    }
    if (tid < HID) {
        h0f[0][tid] = (_Float16)0.f; h0f[1][tid] = (_Float16)0.f;
        h1f[0][tid] = (_Float16)0.f; h1f[1][tid] = (_Float16)0.f;
        h2f[0][tid] = (_Float16)0.f; h2f[1][tid] = (_Float16)0.f;
    }

    // exp2-space scale for this lane's gate class (g -> tanh -> -2log2e).
    const bool  isg = (cls == 2);
    const float sE  = isg ? (-2.f * LOG2E) : (-LOG2E);
    const float sA  = isg ?  2.f :  1.f;
    const float sB  = isg ? -1.f :  0.f;

    uint32_t wh[32], wi[32];           // packed f16 weights, pre-scaled by sE
    float wx0 = 0.f, bj = 0.f;
    if (stage == 0) {
        wx0 = Wih0[row] * sE;          // Wih0 is [256,1]
        bj  = (bih0[row] + bhh0[row]) * sE;
        cvt_row(Whh0, row, sE, wh);
        cvt_row(Wih1, row, sE, wi);    // p1 task (consumer has same cls)
    } else if (stage == 1) {
        bj = (bih1[row] + bhh1[row]) * sE;
        cvt_row(Whh1, row, sE, wh);
        cvt_row(Wih2, row, sE, wi);    // p2 task
    } else {
        bj = (bih2[row] + bhh2[row]) * sE;
        cvt_row(Whh2, row, sE, wh);
        #pragma unroll
        for (int k = 0; k < 32; ++k) wi[k] = 0;
    }

    // Hoisted, pre-offset LDS pointers (zero per-iter address math).
    _Float16* ring = (stage == 0) ? h0f[0] : (stage == 1) ? h1f[0] : h2f[0];
    const uint4* Ard0 = reinterpret_cast<const uint4*>(ring);          // slot 0
    const uint4* Ard1 = reinterpret_cast<const uint4*>(ring + HID);    // slot 1
    _Float16* Awr0 = ring + hidx;
    _Float16* Awr1 = ring + HID + hidx;
    const float* Pin0  = (stage == 1) ? &p1buf[0][pidx] : &p2buf[0][pidx];
    const float* Pin1  = (stage == 1) ? &p1buf[1][pidx] : &p2buf[1][pidx];
    float* Pout0 = (stage == 0) ? &p1buf[0][pidx] : &p2buf[0][pidx];
    float* Pout1 = (stage == 0) ? &p1buf[1][pidx] : &p2buf[1][pidx];
    const int soff = 2 * stage;

    float c = 0.f;                     // cell state (4 consistent quad copies)
    __syncthreads();

    int s = 0;
    #pragma unroll 1
    for (int it = 0; it < NITER / 2; ++it) {
        // ---------- half A: s even -> rd slot 1, wr slot 0 ----------
        {
            HV v = load_h8(Ard1);
            float a0;
            if (stage == 0) a0 = fmaf(wx0, xs[s], bj);
            else            a0 = bj + Pin1[0];
            float acc = dot64v(wh, v, a0);          // already in exp2 space
            if (stage < 2) Pout0[0] = dot64v(wi, v, 0.f);
            float a = fmaf(sA, RCPF(1.f + EXP2F(acc)), sB);
            float gi = qbcast<0x00>(a), gf = qbcast<0x55>(a);
            float gg = qbcast<0xAA>(a), go = qbcast<0xFF>(a);
            if ((unsigned)(s - soff) < (unsigned)T_LEN) {
                c = fmaf(gf, c, gi * gg);
                float tc = fmaf(2.f, RCPF(1.f + EXP2F(-2.f * LOG2E * c)), -1.f);
                float h  = go * tc;
                if (cls0) Awr0[0] = (_Float16)h;
            }
            __syncthreads();
            ++s;
        }
        // ---------- half B: s odd -> rd slot 0, wr slot 1 ----------
        {
            HV v = load_h8(Ard0);
            float a0;
            if (stage == 0) a0 = fmaf(wx0, xs[s], bj);
            else            a0 = bj + Pin0[0];
            float acc = dot64v(wh, v, a0);
            if (stage < 2) Pout1[0] = dot64v(wi, v, 0.f);
            float a = fmaf(sA, RCPF(1.f + EXP2F(acc)), sB);
            float gi = qbcast<0x00>(a), gf = qbcast<0x55>(a);
            float gg = qbcast<0xAA>(a), go = qbcast<0xFF>(a);
            if ((unsigned)(s - soff) < (unsigned)T_LEN) {
                c = fmaf(gf, c, gi * gg);
                float tc = fmaf(2.f, RCPF(1.f + EXP2F(-2.f * LOG2E * c)), -1.f);
                float h  = go * tc;
                if (cls0) Awr1[0] = (_Float16)h;
            }
            __syncthreads();
            ++s;
        }
    }

    // Final FC (f32). Last stage-2 write: s=2051 -> slot 1 => h2f[1] = h2[T-1].
    if (tid < EMB) {
        float acc = fcb[tid];
        const _Float16* hf = h2f[1];
        const float4* W4 = reinterpret_cast<const float4*>(fcW + tid * HID);
        #pragma unroll
        for (int k = 0; k < 16; ++k) {
            float4 wv4 = W4[k];
            acc = fmaf(wv4.x, (float)hf[4 * k + 0], acc);
            acc = fmaf(wv4.y, (float)hf[4 * k + 1], acc);
            acc = fmaf(wv4.z, (float)hf[4 * k + 2], acc);
            acc = fmaf(wv4.w, (float)hf[4 * k + 3], acc);
        }
        out[b * EMB + tid] = acc;
    }
}

extern "C" void kernel_launch(void* const* d_in, const int* in_sizes, int n_in,
                              void* d_out, int out_size, void* d_ws, size_t ws_size,
                              hipStream_t stream) {
    const float* x    = (const float*)d_in[0];
    const float* Wih0 = (const float*)d_in[1];
    const float* Whh0 = (const float*)d_in[2];
    const float* bih0 = (const float*)d_in[3];
    const float* bhh0 = (const float*)d_in[4];
    const float* Wih1 = (const float*)d_in[5];
    const float* Whh1 = (const float*)d_in[6];
    const float* bih1 = (const float*)d_in[7];
    const float* bhh1 = (const float*)d_in[8];
    const float* Wih2 = (const float*)d_in[9];
    const float* Whh2 = (const float*)d_in[10];
    const float* bih2 = (const float*)d_in[11];
    const float* bhh2 = (const float*)d_in[12];
    const float* fcW  = (const float*)d_in[13];
    const float* fcb  = (const float*)d_in[14];
    float* out = (float*)d_out;

    lstm3_fused<<<dim3(256), dim3(768), 0, stream>>>(
        x, Wih0, Whh0, bih0, bhh0,
        Wih1, Whh1, bih1, bhh1,
        Wih2, Whh2, bih2, bhh2,
        fcW, fcb, out);
}